// Round 10
// baseline (400.278 us; speedup 1.0000x reference)
//
#include <hip/hip_runtime.h>

// Round 30: 2-wave split-gather k_layer (test per-wave request-queue hypothesis).
// - Block = 128 thr. Wave0 gathers first half of each row's list, wave1 second
//   half; wave1 writes partial ag into ltw; one __syncthreads; wave0 combines,
//   runs GEMM+epilogue (unchanged); wave1 retires. Gather waves 3125 -> 6250
//   (12 -> ~20 resident waves/CU). LDS unchanged (partial aliases ltw).
// - k_poolsum: u16 scalar loads -> uint (2 cols/thread, 64-thr blocks).

#define H 128
#define PPG 16
#define BKSH 8                 // 256 nodes per bucket
#define CH 4096                // edges per scatter block

typedef unsigned short u16;
typedef unsigned char u8;
typedef __attribute__((ext_vector_type(8))) short bf16x8;
typedef __attribute__((ext_vector_type(4))) float f32x4;
typedef __attribute__((ext_vector_type(2))) float f32x2;

__device__ __forceinline__ float b2f(u16 u){ return __uint_as_float(((unsigned)u) << 16); }
__device__ __forceinline__ u16 f2b(float f){
    unsigned x = __float_as_uint(f);
    unsigned r = x + 0x7fffu + ((x >> 16) & 1u);   // RNE fp32->bf16
    return (u16)(r >> 16);
}
__device__ __forceinline__ bf16x8 cvt8(const float* __restrict__ p){
    bf16x8 v;
    #pragma unroll
    for (int j = 0; j < 8; j++) v[j] = (short)f2b(p[j]);
    return v;
}
// pack 8 f32 -> 8 fp8 (e4m3, RNE) as uint2
__device__ __forceinline__ uint2 pk_fp8(const float* nv){
    int lo = 0, hi = 0;
    lo = __builtin_amdgcn_cvt_pk_fp8_f32(nv[0], nv[1], lo, false);
    lo = __builtin_amdgcn_cvt_pk_fp8_f32(nv[2], nv[3], lo, true);
    hi = __builtin_amdgcn_cvt_pk_fp8_f32(nv[4], nv[5], hi, false);
    hi = __builtin_amdgcn_cvt_pk_fp8_f32(nv[6], nv[7], hi, true);
    uint2 r; r.x = (unsigned)lo; r.y = (unsigned)hi; return r;
}
__device__ __forceinline__ void acc_fp8w(float* ag, unsigned x, unsigned y){
    f32x2 d0 = __builtin_amdgcn_cvt_pk_f32_fp8((int)x, false);
    f32x2 d1 = __builtin_amdgcn_cvt_pk_f32_fp8((int)x, true);
    f32x2 d2 = __builtin_amdgcn_cvt_pk_f32_fp8((int)y, false);
    f32x2 d3 = __builtin_amdgcn_cvt_pk_f32_fp8((int)y, true);
    ag[0] += d0[0]; ag[1] += d0[1];
    ag[2] += d1[0]; ag[3] += d1[1];
    ag[4] += d2[0]; ag[5] += d2[1];
    ag[6] += d3[0]; ag[7] += d3[1];
}
// permuted fp8 offset for fragment (q,kk) within a row
__device__ __forceinline__ int fp8_off(int q, int kk){
    return (kk < 2) ? (q * 16 + kk * 8) : (64 + q * 16 + (kk - 2) * 8);
}
__device__ __forceinline__ void lds_fence(){
    asm volatile("s_waitcnt lgkmcnt(0)" ::: "memory");
    __builtin_amdgcn_sched_barrier(0);
}

// ---------------- weight pre-convert (merged) ----------------
__global__ __launch_bounds__(256) void k_splitall(const float* __restrict__ W_in, const float* __restrict__ sWl,
                                                  const float* __restrict__ sWr, const float* __restrict__ ipW,
                                                  u16* __restrict__ Win, u16* __restrict__ Wl,
                                                  u16* __restrict__ Wr, u16* __restrict__ Wv){
    const int WSZ = H * H;
    int i = blockIdx.x * 256 + threadIdx.x;
    if (i < WSZ)               Win[i]           = f2b(W_in[i]);
    else if (i < 4 * WSZ)      Wl[i - WSZ]      = f2b(sWl[i - WSZ]);
    else if (i < 7 * WSZ)      Wr[i - 4 * WSZ]  = f2b(sWr[i - 4 * WSZ]);
    else if (i < 8 * WSZ)      Wv[i - 7 * WSZ]  = f2b(ipW[2 * WSZ + (i - 7 * WSZ)]);
}

// ---------------- bucketed CSR build ----------------
__global__ __launch_bounds__(1024) void k_bcnt(const int* __restrict__ dst, int* __restrict__ bcnt,
                                               int E, int NBK){
    __shared__ int cnt[256];
    int tid = threadIdx.x;
    if (tid < 256) cnt[tid] = 0;
    __syncthreads();
    int e0 = blockIdx.x * CH;
    int n = min(CH, E - e0);
    for (int j = tid; j < n; j += 1024) atomicAdd(&cnt[dst[e0 + j] >> BKSH], 1);
    __syncthreads();
    if (tid < NBK && cnt[tid]) atomicAdd(&bcnt[tid], cnt[tid]);
}

__global__ __launch_bounds__(256) void k_bscan(const int* __restrict__ bcnt, int* __restrict__ boff,
                                               int* __restrict__ bcur, int* __restrict__ offs, int NBK, int N){
    __shared__ int pre[256];
    int tid = threadIdx.x;
    int v = (tid < NBK) ? bcnt[tid] : 0;
    pre[tid] = v;
    __syncthreads();
    for (int off = 1; off < 256; off <<= 1){
        int a = (tid >= off) ? pre[tid - off] : 0;
        __syncthreads();
        pre[tid] += a;
        __syncthreads();
    }
    int excl = pre[tid] - v;
    if (tid < NBK){ boff[tid] = excl; bcur[tid] = excl; }
    if (tid == 255){
        boff[NBK] = pre[255];
        offs[N] = pre[255];
    }
}

__global__ __launch_bounds__(1024) void k_bscatter(const int* __restrict__ src, const int* __restrict__ dst,
                                                   unsigned* __restrict__ ebuf, int* __restrict__ bcur,
                                                   int E, int NBK){
    __shared__ int cnt[256], pre[256], loc[256], lcur[256], base[256];
    __shared__ unsigned stage[CH];
    int tid = threadIdx.x;
    if (tid < 256){ cnt[tid] = 0; }
    __syncthreads();
    int e0 = blockIdx.x * CH;
    int n = min(CH, E - e0);
    for (int j = tid; j < n; j += 1024) atomicAdd(&cnt[dst[e0 + j] >> BKSH], 1);
    __syncthreads();
    if (tid < NBK) base[tid] = atomicAdd(&bcur[tid], cnt[tid]);
    if (tid < 256) pre[tid] = cnt[tid];
    __syncthreads();
    for (int off = 1; off < 256; off <<= 1){
        int v = (tid < 256 && tid >= off) ? pre[tid - off] : 0;
        __syncthreads();
        if (tid < 256) pre[tid] += v;
        __syncthreads();
    }
    if (tid < 256){ loc[tid] = pre[tid] - cnt[tid]; lcur[tid] = loc[tid]; }
    __syncthreads();
    for (int j = tid; j < n; j += 1024){
        int d = dst[e0 + j], s = src[e0 + j];
        int k = d >> BKSH;
        int p = atomicAdd(&lcur[k], 1);
        stage[p] = (unsigned)d | ((unsigned)s << 16);
    }
    __syncthreads();
    for (int j = tid; j < n; j += 1024){
        unsigned v = stage[j];
        int k = (v & 0xffffu) >> BKSH;
        ebuf[base[k] + (j - loc[k])] = v;
    }
}

__global__ __launch_bounds__(256) void k_bfill(const unsigned* __restrict__ ebuf, const int* __restrict__ boff,
                                               int* __restrict__ offs, int* __restrict__ csr,
                                               float* __restrict__ invdeg, int N){
    __shared__ int deg[256], pre[256], cur[256];
    int k = blockIdx.x, tid = threadIdx.x;
    int node0 = k << BKSH;
    int s0 = boff[k], s1 = boff[k + 1];
    deg[tid] = 0;
    __syncthreads();
    for (int j = s0 + tid; j < s1; j += 256) atomicAdd(&deg[ebuf[j] & 255u], 1);
    __syncthreads();
    pre[tid] = deg[tid];
    __syncthreads();
    for (int off = 1; off < 256; off <<= 1){
        int v = (tid >= off) ? pre[tid - off] : 0;
        __syncthreads();
        pre[tid] += v;
        __syncthreads();
    }
    int excl = pre[tid] - deg[tid];
    int node = node0 + tid;
    if (node < N){
        offs[node] = s0 + excl;
        invdeg[node] = 1.0f / (float)max(deg[tid], 1);
    }
    cur[tid] = s0 + excl;
    __syncthreads();
    for (int j = s0 + tid; j < s1; j += 256){
        unsigned v = ebuf[j];
        int p = atomicAdd(&cur[v & 255u], 1);
        csr[p] = (int)(v >> 16);
    }
}

__global__ void k_start(const int* __restrict__ batch, int* __restrict__ start, int N, int B){
    int n = blockIdx.x * blockDim.x + threadIdx.x;
    if (n >= N) return;
    int b = batch[n];
    int bp = (n == 0) ? -1 : batch[n - 1];
    for (int g = bp + 1; g <= b; g++) start[g] = n;
    if (n == N - 1){ for (int g = b + 1; g <= B; g++) start[g] = N; }
}

// ---------------- input projection GEMM ----------------
__global__ __launch_bounds__(256) void k_gemm0(const float* __restrict__ A, u16* __restrict__ Xb,
                                               u8* __restrict__ X8,
                                               const u16* __restrict__ W1, const float* __restrict__ bias,
                                               int nrows){
    __shared__ float lt[4][16][132];
    const int wave = threadIdx.x >> 6;
    const int l = threadIdx.x & 63;
    const int q = l >> 4;
    const int t = l & 15;
    const int row0 = blockIdx.x * 64 + wave * 16;
    const int rowA = min(row0 + t, nrows - 1);
    bf16x8 a1[4];
    const float* p = A + (size_t)rowA * H + q * 8;
    #pragma unroll
    for (int kk = 0; kk < 4; kk++) a1[kk] = cvt8(p + kk * 32);
    f32x4 acc[8];
    #pragma unroll
    for (int nt = 0; nt < 8; nt++){
        f32x4 c = {0.f, 0.f, 0.f, 0.f};
        const size_t wof = (size_t)(nt * 16 + t) * H + q * 8;
        #pragma unroll
        for (int kk = 0; kk < 4; kk++)
            c = __builtin_amdgcn_mfma_f32_16x16x32_bf16(a1[kk], *(const bf16x8*)(W1 + wof + kk * 32), c, 0, 0, 0);
        acc[nt] = c;
    }
    float bv[8];
    #pragma unroll
    for (int nt = 0; nt < 8; nt++) bv[nt] = bias[nt * 16 + t];
    #pragma unroll
    for (int r = 0; r < 4; r++)
        #pragma unroll
        for (int nt = 0; nt < 8; nt++)
            lt[wave][q * 4 + r][nt * 16 + t] = fmaxf(acc[nt][r] + bv[nt], 0.f);
    lds_fence();
    const int row = row0 + t;
    if (row < nrows){
        #pragma unroll
        for (int kk = 0; kk < 4; kk++){
            const float* lp = &lt[wave][t][q * 8 + kk * 32];
            float4 v0 = *(const float4*)lp;
            float4 v1 = *(const float4*)(lp + 4);
            float nv[8] = {v0.x, v0.y, v0.z, v0.w, v1.x, v1.y, v1.z, v1.w};
            bf16x8 o;
            #pragma unroll
            for (int j = 0; j < 8; j++) o[j] = (short)f2b(nv[j]);
            *(bf16x8*)(Xb + (size_t)row * H + q * 8 + kk * 32) = o;
            *(uint2*)(X8 + (size_t)row * H + fp8_off(q, kk)) = pk_fp8(nv);
        }
    }
}

// ---------------- fused layer: 2-wave split fp8 gather + SAGE GEMM + LN + relu + residual ----------------
// Block = 128 thr (2 waves). Wave0: first half-lists + GEMM + epilogue.
// Wave1: second half-lists -> partial into ltw -> retire.
template<bool FSC>
__global__ __launch_bounds__(128) void k_layer(
    const u16* __restrict__ Xin, const u8* __restrict__ Xin8,
    u16* __restrict__ Xout, u8* __restrict__ Xout8,
    const int* __restrict__ offs, const int* __restrict__ csr, const float* __restrict__ invdeg,
    const u16* __restrict__ W1, const u16* __restrict__ W2,
    const float* __restrict__ bias, const float* __restrict__ lng, const float* __restrict__ lnb,
    u16* __restrict__ Vb, const u16* __restrict__ Wv, const float* __restrict__ vbias,
    const float* __restrict__ qk, const float* __restrict__ qkb, float* __restrict__ scores,
    int nrows)
{
    __shared__ float ltw[16 * 132];
    const int wave = threadIdx.x >> 6;
    const int l = threadIdx.x & 63;
    const int q = l >> 4;
    const int t = l & 15;
    const int myrow = blockIdx.x * 16 + t;
    const bool valid = myrow < nrows;
    const int rowA = min(myrow, nrows - 1);

    // residual / lin_r operand: wave0 only
    bf16x8 a2[4];
    if (wave == 0){
        const u16* px = Xin + (size_t)rowA * H + q * 8;
        #pragma unroll
        for (int kk = 0; kk < 4; kk++) a2[kk] = *(const bf16x8*)(px + kk * 32);
    }
    // fp8 permuted gather over this wave's half of the list
    float ag[4][8];
    #pragma unroll
    for (int kk = 0; kk < 4; kk++)
        #pragma unroll
        for (int j = 0; j < 8; j++) ag[kk][j] = 0.f;
    int o0 = valid ? offs[myrow] : 0;
    int o1 = valid ? offs[myrow + 1] : 0;
    int mid = o0 + ((o1 - o0 + 1) >> 1);
    int i  = wave ? mid : o0;
    int ie = wave ? o1 : mid;
    int p0 = 0, p1 = 0, p2 = 0, p3 = 0;
    if (i + 3 < ie){ p0 = csr[i]; p1 = csr[i + 1]; p2 = csr[i + 2]; p3 = csr[i + 3]; }
    while (i + 3 < ie){
        int t0 = p0, t1 = p1, t2 = p2, t3 = p3;
        int nx = i + 4;
        if (nx + 3 < ie){ p0 = csr[nx]; p1 = csr[nx + 1]; p2 = csr[nx + 2]; p3 = csr[nx + 3]; }
        const u8* g0 = Xin8 + (size_t)t0 * H + q * 16;
        const u8* g1 = Xin8 + (size_t)t1 * H + q * 16;
        const u8* g2 = Xin8 + (size_t)t2 * H + q * 16;
        const u8* g3 = Xin8 + (size_t)t3 * H + q * 16;
        uint4 a0 = *(const uint4*)(g0);
        uint4 b0 = *(const uint4*)(g0 + 64);
        uint4 a1v = *(const uint4*)(g1);
        uint4 b1 = *(const uint4*)(g1 + 64);
        uint4 a2v = *(const uint4*)(g2);
        uint4 b2 = *(const uint4*)(g2 + 64);
        uint4 a3 = *(const uint4*)(g3);
        uint4 b3 = *(const uint4*)(g3 + 64);
        acc_fp8w(ag[0], a0.x, a0.y);  acc_fp8w(ag[1], a0.z, a0.w);
        acc_fp8w(ag[2], b0.x, b0.y);  acc_fp8w(ag[3], b0.z, b0.w);
        acc_fp8w(ag[0], a1v.x, a1v.y); acc_fp8w(ag[1], a1v.z, a1v.w);
        acc_fp8w(ag[2], b1.x, b1.y);  acc_fp8w(ag[3], b1.z, b1.w);
        acc_fp8w(ag[0], a2v.x, a2v.y); acc_fp8w(ag[1], a2v.z, a2v.w);
        acc_fp8w(ag[2], b2.x, b2.y);  acc_fp8w(ag[3], b2.z, b2.w);
        acc_fp8w(ag[0], a3.x, a3.y);  acc_fp8w(ag[1], a3.z, a3.w);
        acc_fp8w(ag[2], b3.x, b3.y);  acc_fp8w(ag[3], b3.z, b3.w);
        i = nx;
    }
    for (; i < ie; i++){
        int s = csr[i];
        const u8* gp = Xin8 + (size_t)s * H + q * 16;
        uint4 wa = *(const uint4*)(gp);
        uint4 wb = *(const uint4*)(gp + 64);
        acc_fp8w(ag[0], wa.x, wa.y);  acc_fp8w(ag[1], wa.z, wa.w);
        acc_fp8w(ag[2], wb.x, wb.y);  acc_fp8w(ag[3], wb.z, wb.w);
    }
    // wave1 deposits partial into ltw (A-layout: row t, col q*8+kk*32+j)
    if (wave == 1){
        float* pw = ltw + t * 132 + q * 8;
        #pragma unroll
        for (int kk = 0; kk < 4; kk++)
            #pragma unroll
            for (int j = 0; j < 8; j++) pw[kk * 32 + j] = ag[kk][j];
    }
    __syncthreads();
    if (wave == 1) return;
    // wave0: combine partial
    {
        const float* pr = ltw + t * 132 + q * 8;
        #pragma unroll
        for (int kk = 0; kk < 4; kk++)
            #pragma unroll
            for (int j = 0; j < 8; j++) ag[kk][j] += pr[kk * 32 + j];
    }
    lds_fence();      // partial reads landed before ltw reuse below
    float idg = valid ? invdeg[myrow] : 0.f;
    bf16x8 a1[4];
    #pragma unroll
    for (int kk = 0; kk < 4; kk++){
        bf16x8 v;
        #pragma unroll
        for (int j = 0; j < 8; j++) v[j] = (short)f2b(ag[kk][j] * idg);
        a1[kk] = v;
    }

    // GEMM: agg@W1^T + x@W2^T
    f32x4 acc[8];
    #pragma unroll
    for (int nt = 0; nt < 8; nt++){
        f32x4 c = {0.f, 0.f, 0.f, 0.f};
        const size_t wof = (size_t)(nt * 16 + t) * H + q * 8;
        #pragma unroll
        for (int kk = 0; kk < 4; kk++)
            c = __builtin_amdgcn_mfma_f32_16x16x32_bf16(a1[kk], *(const bf16x8*)(W1 + wof + kk * 32), c, 0, 0, 0);
        #pragma unroll
        for (int kk = 0; kk < 4; kk++)
            c = __builtin_amdgcn_mfma_f32_16x16x32_bf16(a2[kk], *(const bf16x8*)(W2 + wof + kk * 32), c, 0, 0, 0);
        acc[nt] = c;
    }
    float bv[8], gv[8], lbv[8];
    #pragma unroll
    for (int nt = 0; nt < 8; nt++){
        int col = nt * 16 + t;
        bv[nt] = bias[col]; gv[nt] = lng[col]; lbv[nt] = lnb[col];
    }
    // phase 1: LN + relu into wave-private LDS tile
    #pragma unroll
    for (int r = 0; r < 4; r++){
        float hv[8], s = 0.f, s2 = 0.f;
        #pragma unroll
        for (int nt = 0; nt < 8; nt++){ float v = acc[nt][r] + bv[nt]; hv[nt] = v; s += v; s2 += v * v; }
        #pragma unroll
        for (int m = 1; m < 16; m <<= 1){ s += __shfl_xor(s, m, 64); s2 += __shfl_xor(s2, m, 64); }
        float mean = s * (1.f / H);
        float var  = s2 * (1.f / H) - mean * mean;
        float rstd = rsqrtf(var + 1e-5f);
        #pragma unroll
        for (int nt = 0; nt < 8; nt++){
            float v = (hv[nt] - mean) * rstd * gv[nt] + lbv[nt];
            ltw[(q * 4 + r) * 132 + nt * 16 + t] = fmaxf(v, 0.f);
        }
    }
    lds_fence();
    // phase 2: row-major read, residual from a2, store / scores / V
    bf16x8 xv[4];
    float sc[4] = {0.f, 0.f, 0.f, 0.f};
    #pragma unroll
    for (int kk = 0; kk < 4; kk++){
        const float* lp = ltw + t * 132 + q * 8 + kk * 32;
        float4 v0 = *(const float4*)lp;
        float4 v1 = *(const float4*)(lp + 4);
        float nv[8] = {v0.x, v0.y, v0.z, v0.w, v1.x, v1.y, v1.z, v1.w};
        #pragma unroll
        for (int j = 0; j < 8; j++) nv[j] += b2f((u16)a2[kk][j]);
        bf16x8 o;
        #pragma unroll
        for (int j = 0; j < 8; j++) o[j] = (short)f2b(nv[j]);
        xv[kk] = o;
        if (FSC){
            #pragma unroll
            for (int h = 0; h < 4; h++){
                const float* qp = qk + h * H + q * 8 + kk * 32;
                float4 q0 = *(const float4*)qp;
                float4 q1 = *(const float4*)(qp + 4);
                sc[h] += nv[0] * q0.x + nv[1] * q0.y + nv[2] * q0.z + nv[3] * q0.w
                       + nv[4] * q1.x + nv[5] * q1.y + nv[6] * q1.z + nv[7] * q1.w;
            }
        } else {
            if (valid){
                *(bf16x8*)(Xout + (size_t)myrow * H + q * 8 + kk * 32) = o;
                *(uint2*)(Xout8 + (size_t)myrow * H + fp8_off(q, kk)) = pk_fp8(nv);
            }
        }
    }
    if (FSC){
        #pragma unroll
        for (int h = 0; h < 4; h++){
            sc[h] += __shfl_xor(sc[h], 16, 64);
            sc[h] += __shfl_xor(sc[h], 32, 64);
        }
        if (q == 0 && valid){
            #pragma unroll
            for (int h = 0; h < 4; h++) scores[myrow * 4 + h] = sc[h] + qkb[h];
        }
        // fused V projection: xv = new-x A-fragments
        f32x4 vacc[8];
        #pragma unroll
        for (int nt = 0; nt < 8; nt++){
            f32x4 c = {0.f, 0.f, 0.f, 0.f};
            const size_t wof = (size_t)(nt * 16 + t) * H + q * 8;
            #pragma unroll
            for (int kk = 0; kk < 4; kk++)
                c = __builtin_amdgcn_mfma_f32_16x16x32_bf16(xv[kk], *(const bf16x8*)(Wv + wof + kk * 32), c, 0, 0, 0);
            vacc[nt] = c;
        }
        float vb2[8];
        #pragma unroll
        for (int nt = 0; nt < 8; nt++) vb2[nt] = vbias[nt * 16 + t];
        #pragma unroll
        for (int r = 0; r < 4; r++)
            #pragma unroll
            for (int nt = 0; nt < 8; nt++)
                ltw[(q * 4 + r) * 132 + nt * 16 + t] = vacc[nt][r] + vb2[nt];
        lds_fence();
        if (valid){
            #pragma unroll
            for (int kk = 0; kk < 4; kk++){
                const float* lp = ltw + t * 132 + q * 8 + kk * 32;
                float4 v0 = *(const float4*)lp;
                float4 v1 = *(const float4*)(lp + 4);
                bf16x8 o;
                o[0] = (short)f2b(v0.x); o[1] = (short)f2b(v0.y);
                o[2] = (short)f2b(v0.z); o[3] = (short)f2b(v0.w);
                o[4] = (short)f2b(v1.x); o[5] = (short)f2b(v1.y);
                o[6] = (short)f2b(v1.z); o[7] = (short)f2b(v1.w);
                *(bf16x8*)(Vb + (size_t)myrow * H + q * 8 + kk * 32) = o;
            }
        }
    }
}

// ---------------- attention fold ----------------
__global__ __launch_bounds__(128) void k_qk(const float* __restrict__ ipW, const float* __restrict__ ipb,
                                            const float* __restrict__ query,
                                            float* __restrict__ qk, float* __restrict__ qkb){
    __shared__ float qs[H];
    int t = threadIdx.x;
    float a = ipb[t];
    for (int c = 0; c < H; c++) a += ipW[t * H + c] * query[c];
    qs[t] = a;
    __syncthreads();
    const float r32 = 0.17677669529663687f;
    #pragma unroll
    for (int h = 0; h < 4; h++){
        float v = 0.f;
        for (int d = 0; d < 32; d++) v += ipW[(H + h * 32 + d) * H + t] * qs[h * 32 + d];
        qk[h * H + t] = v * r32;
    }
    if (t < 4){
        float z = 0.f;
        for (int d = 0; d < 32; d++) z += ipb[H + t * 32 + d] * qs[t * 32 + d];
        qkb[t] = z * r32;
    }
}

// ---------------- parallel softmax pool ----------------
__global__ __launch_bounds__(256) void k_smax(const float* __restrict__ scores, const int* __restrict__ start,
                                              float* __restrict__ smax, int B){
    int idx = blockIdx.x * 4 + (threadIdx.x >> 6);
    if (idx >= B * 4) return;
    int b = idx >> 2, h = idx & 3, l = threadIdx.x & 63;
    int s0 = start[b], s1 = start[b + 1];
    float m = -1e30f;
    for (int n = s0 + l; n < s1; n += 64) m = fmaxf(m, scores[n * 4 + h]);
    #pragma unroll
    for (int s = 1; s < 64; s <<= 1) m = fmaxf(m, __shfl_xor(m, s, 64));
    if (l == 0) smax[idx] = m;
}

__global__ __launch_bounds__(64) void k_poolsum(const float* __restrict__ scores, const u16* __restrict__ Vb,
                                                const int* __restrict__ start, const float* __restrict__ smax,
                                                float* __restrict__ praw, float* __restrict__ den){
    int b = blockIdx.x / PPG, p = blockIdx.x % PPG;
    int c2 = threadIdx.x;              // 0..63: cols 2*c2, 2*c2+1
    int h = c2 >> 4;
    int s0 = start[b], s1 = start[b + 1];
    float sm = smax[b * 4 + h];
    float a0 = 0.f, a1 = 0.f, se = 0.f;
    for (int n = s0 + p; n < s1; n += PPG){
        float e = expf(scores[n * 4 + h] - sm);
        unsigned wv = *(const unsigned*)(Vb + (size_t)n * H + 2 * c2);
        a0 += e * b2f((u16)(wv & 0xffffu));
        a1 += e * b2f((u16)(wv >> 16));
        se += e;
    }
    atomicAdd(&praw[b * H + 2 * c2], a0);
    atomicAdd(&praw[b * H + 2 * c2 + 1], a1);
    if ((c2 & 15) == 0) atomicAdd(&den[b * 4 + h], se);
}

// ---------------- tail ----------------
__global__ __launch_bounds__(128) void k_tail(
    const float* __restrict__ praw, const float* __restrict__ den,
    const float* __restrict__ outW, const float* __restrict__ outb,
    const float* __restrict__ symfeat, const float* __restrict__ symW, const float* __restrict__ symb,
    const float* __restrict__ sfW, const float* __restrict__ sfb, const float* __restrict__ sfg, const float* __restrict__ sfbeta,
    const float* __restrict__ fusW, const float* __restrict__ fusb, const float* __restrict__ fusg, const float* __restrict__ fusbeta,
    const float* __restrict__ hW1, const float* __restrict__ hb1, const float* __restrict__ hW2, const float* __restrict__ hb2,
    float* __restrict__ dout, int B){
    int b = blockIdx.x, t = threadIdx.x;
    __shared__ float P[H], G[H], EMB[H], S[H], F[H], HHs[192], red[H], mm[2];
    float dh = den[b * 4 + (t >> 5)];
    P[t] = (dh > 0.f) ? praw[b * H + t] / dh : 0.f;
    __syncthreads();
    float a = outb[t];
    for (int c = 0; c < H; c++) a += P[c] * outW[t * H + c];
    G[t] = a;
    {
        int f = t >> 5;
        float e = symb[t];
        for (int i = 0; i < 16; i++) e += symfeat[b * 64 + f * 16 + i] * symW[t * 16 + i];
        EMB[t] = fmaxf(e, 0.f);
    }
    __syncthreads();
    float a2 = sfb[t];
    for (int c = 0; c < H; c++) a2 += EMB[c] * sfW[t * H + c];
    a2 = fmaxf(a2, 0.f);
    red[t] = a2; __syncthreads();
    for (int s = 64; s > 0; s >>= 1){ if (t < s) red[t] += red[t + s]; __syncthreads(); }
    if (t == 0) mm[0] = red[0];
    __syncthreads();
    red[t] = a2 * a2; __syncthreads();
    for (int s = 64; s > 0; s >>= 1){ if (t < s) red[t] += red[t + s]; __syncthreads(); }
    if (t == 0) mm[1] = red[0];
    __syncthreads();
    {
        float mean = mm[0] * (1.f / H), var = mm[1] * (1.f / H) - mean * mean;
        float rstd = rsqrtf(var + 1e-5f);
        S[t] = (a2 - mean) * rstd * sfg[t] + sfbeta[t];
    }
    __syncthreads();
    float fu = fusb[t];
    for (int c = 0; c < H; c++) fu += G[c] * fusW[t * 256 + c];
    for (int c = 0; c < H; c++) fu += S[c] * fusW[t * 256 + 128 + c];
    fu = fmaxf(fu, 0.f);
    red[t] = fu; __syncthreads();
    for (int s = 64; s > 0; s >>= 1){ if (t < s) red[t] += red[t + s]; __syncthreads(); }
    if (t == 0) mm[0] = red[0];
    __syncthreads();
    red[t] = fu * fu; __syncthreads();
    for (int s = 64; s > 0; s >>= 1){ if (t < s) red[t] += red[t + s]; __syncthreads(); }
    if (t == 0) mm[1] = red[0];
    __syncthreads();
    {
        float mean = mm[0] * (1.f / H), var = mm[1] * (1.f / H) - mean * mean;
        float rstd = rsqrtf(var + 1e-5f);
        F[t] = (fu - mean) * rstd * fusg[t] + fusbeta[t];
    }
    __syncthreads();
    for (int idx = t; idx < 192; idx += 128){
        float hv = hb1[idx];
        for (int c = 0; c < H; c++) hv += F[c] * hW1[idx * H + c];
        HHs[idx] = fmaxf(hv, 0.f);
    }
    __syncthreads();
    if (t < 3){
        float z = hb2[t];
        for (int o = 0; o < 64; o++) z += HHs[t * 64 + o] * hW2[t * 64 + o];
        dout[t * B + b] = 1.f / (1.f + expf(-z));
    }
}

extern "C" void kernel_launch(void* const* d_in, const int* in_sizes, int n_in,
                              void* d_out, int out_size, void* d_ws, size_t ws_size,
                              hipStream_t stream){
    const float* NF      = (const float*)d_in[0];
    const float* SYMF    = (const float*)d_in[1];
    const int*   EIDX    = (const int*)d_in[2];
    const int*   BATCH   = (const int*)d_in[3];
    const float* W_in    = (const float*)d_in[4];
    const float* b_in    = (const float*)d_in[5];
    const float* sWl     = (const float*)d_in[6];
    const float* sbl     = (const float*)d_in[7];
    const float* sWr     = (const float*)d_in[8];
    const float* lng     = (const float*)d_in[9];
    const float* lnb     = (const float*)d_in[10];
    const float* query   = (const float*)d_in[11];
    const float* ipW     = (const float*)d_in[12];
    const float* ipb     = (const float*)d_in[13];
    const float* outW    = (const float*)d_in[14];
    const float* outb    = (const float*)d_in[15];
    const float* symW    = (const float*)d_in[16];
    const float* symb    = (const float*)d_in[17];
    const float* sfW     = (const float*)d_in[18];
    const float* sfb     = (const float*)d_in[19];
    const float* sfg     = (const float*)d_in[20];
    const float* sfbeta  = (const float*)d_in[21];
    const float* fusW    = (const float*)d_in[22];
    const float* fusb    = (const float*)d_in[23];
    const float* fusg    = (const float*)d_in[24];
    const float* fusbeta = (const float*)d_in[25];
    const float* hW1     = (const float*)d_in[26];
    const float* hb1     = (const float*)d_in[27];
    const float* hW2     = (const float*)d_in[28];
    const float* hb2     = (const float*)d_in[29];

    const int N = in_sizes[0] / H;
    const int E = in_sizes[2] / 2;
    const int B = in_sizes[1] / 64;
    const int* esrc = EIDX;
    const int* edst = EIDX + E;
    const int NBK = (N + 255) >> BKSH;

    char* w = (char*)d_ws;
    auto alloc = [&](size_t bytes) -> char* {
        char* p = w; w += (bytes + 255) & ~(size_t)255; return p;
    };
    u16*   X0      = (u16*)alloc((size_t)N * H * 2);
    u16*   X1      = (u16*)alloc((size_t)N * H * 2);
    u8*    X0q     = (u8*)alloc((size_t)N * H);
    u8*    X1q     = (u8*)alloc((size_t)N * H);
    u16*   Vb      = (u16*)alloc((size_t)N * H * 2);
    float* scores  = (float*)alloc((size_t)N * 4 * 4);
    unsigned* ebuf = (unsigned*)alloc((size_t)E * 4);
    char* zbase    = w;
    int* bcnt      = (int*)alloc((size_t)NBK * 4);
    float* praw    = (float*)alloc((size_t)B * H * 4);
    float* den     = (float*)alloc((size_t)B * 4 * 4);
    size_t zbytes  = (size_t)(w - zbase);
    int* boff      = (int*)alloc((size_t)(NBK + 1) * 4);
    int* bcur      = (int*)alloc((size_t)NBK * 4);
    int* offs      = (int*)alloc((size_t)(N + 1) * 4);
    float* invdeg  = (float*)alloc((size_t)N * 4);
    int* csr       = (int*)alloc((size_t)E * 4);
    int* start     = (int*)alloc((size_t)(B + 1) * 4);
    float* smax    = (float*)alloc((size_t)B * 4 * 4);
    float* qk      = (float*)alloc((size_t)4 * H * 4);
    float* qkb     = (float*)alloc(4 * 4);
    const int WSZ  = H * H;
    u16* Win = (u16*)alloc(WSZ * 2);
    u16* Wl  = (u16*)alloc(3 * WSZ * 2);
    u16* Wr  = (u16*)alloc(3 * WSZ * 2);
    u16* Wv  = (u16*)alloc(WSZ * 2);

    hipMemsetAsync(zbase, 0, zbytes, stream);

    const int cb = (E + CH - 1) / CH;
    k_bcnt<<<cb, 1024, 0, stream>>>(edst, bcnt, E, NBK);
    k_bscan<<<1, 256, 0, stream>>>(bcnt, boff, bcur, offs, NBK, N);
    k_bscatter<<<cb, 1024, 0, stream>>>(esrc, edst, ebuf, bcur, E, NBK);
    k_bfill<<<NBK, 256, 0, stream>>>(ebuf, boff, offs, csr, invdeg, N);
    k_start<<<(N + 255) / 256, 256, 0, stream>>>(BATCH, start, N, B);
    k_qk<<<1, 128, 0, stream>>>(ipW, ipb, query, qk, qkb);
    k_splitall<<<(8 * WSZ + 255) / 256, 256, 0, stream>>>(W_in, sWl, sWr, ipW, Win, Wl, Wr, Wv);

    const int gb = (N + 63) / 64;
    const int lb = (N + 15) / 16;
    k_gemm0<<<gb, 256, 0, stream>>>(NF, X0, X0q, Win, b_in, N);
    // layer 0: X0 -> X1 ; layer 1: X1 -> X0 ; layer 2 (FSC): X0 -> (scores, Vb)
    k_layer<false><<<lb, 128, 0, stream>>>(X0, X0q, X1, X1q, offs, csr, invdeg,
                                           Wl + 0 * WSZ, Wr + 0 * WSZ,
                                           sbl + 0 * H, lng + 0 * H, lnb + 0 * H,
                                           nullptr, nullptr, nullptr,
                                           nullptr, nullptr, nullptr, N);
    k_layer<false><<<lb, 128, 0, stream>>>(X1, X1q, X0, X0q, offs, csr, invdeg,
                                           Wl + 1 * WSZ, Wr + 1 * WSZ,
                                           sbl + 1 * H, lng + 1 * H, lnb + 1 * H,
                                           nullptr, nullptr, nullptr,
                                           nullptr, nullptr, nullptr, N);
    k_layer<true><<<lb, 128, 0, stream>>>(X0, X0q, nullptr, nullptr, offs, csr, invdeg,
                                          Wl + 2 * WSZ, Wr + 2 * WSZ,
                                          sbl + 2 * H, lng + 2 * H, lnb + 2 * H,
                                          Vb, Wv, ipb + 2 * H,
                                          qk, qkb, scores, N);
    k_smax<<<B, 256, 0, stream>>>(scores, start, smax, B);
    k_poolsum<<<B * PPG, 64, 0, stream>>>(scores, Vb, start, smax, praw, den);
    k_tail<<<B, 128, 0, stream>>>(praw, den, outW, outb, SYMF, symW, symb,
                                  sfW, sfb, sfg, sfbeta, fusW, fusb, fusg, fusbeta,
                                  hW1, hb1, hW2, hb2, (float*)d_out, B);
}

// Round 11
// 398.303 us; speedup vs baseline: 1.0050x; 1.0050x over previous
//
#include <hip/hip_runtime.h>

// Round 31: coalesce all non-gather memory ops via LDS staging.
// - k_gemm0: coalesced float4 A-stage -> LDS bf16 tile (stride 136, aliased in
//   lt); frag ds_reads; linear-lane coalesced Xb/X8 stores. ~8x fewer requests.
// - k_layer: cooperative coalesced Xin stage into sx (feeds a2 frags + phase-2
//   residual); non-FSC phase2 linear-lane coalesced Xout/Xout8 stores.
// - Gather itself unchanged (round-9 permuted fp8, 2 req/edge — proven).

#define H 128
#define PPG 16
#define BKSH 8                 // 256 nodes per bucket
#define CH 4096                // edges per scatter block

typedef unsigned short u16;
typedef unsigned char u8;
typedef __attribute__((ext_vector_type(8))) short bf16x8;
typedef __attribute__((ext_vector_type(4))) float f32x4;
typedef __attribute__((ext_vector_type(2))) float f32x2;

__device__ __forceinline__ float b2f(u16 u){ return __uint_as_float(((unsigned)u) << 16); }
__device__ __forceinline__ u16 f2b(float f){
    unsigned x = __float_as_uint(f);
    unsigned r = x + 0x7fffu + ((x >> 16) & 1u);   // RNE fp32->bf16
    return (u16)(r >> 16);
}
// pack 8 f32 -> 8 fp8 (e4m3, RNE) as uint2
__device__ __forceinline__ uint2 pk_fp8(const float* nv){
    int lo = 0, hi = 0;
    lo = __builtin_amdgcn_cvt_pk_fp8_f32(nv[0], nv[1], lo, false);
    lo = __builtin_amdgcn_cvt_pk_fp8_f32(nv[2], nv[3], lo, true);
    hi = __builtin_amdgcn_cvt_pk_fp8_f32(nv[4], nv[5], hi, false);
    hi = __builtin_amdgcn_cvt_pk_fp8_f32(nv[6], nv[7], hi, true);
    uint2 r; r.x = (unsigned)lo; r.y = (unsigned)hi; return r;
}
__device__ __forceinline__ void acc_fp8w(float* ag, unsigned x, unsigned y){
    f32x2 d0 = __builtin_amdgcn_cvt_pk_f32_fp8((int)x, false);
    f32x2 d1 = __builtin_amdgcn_cvt_pk_f32_fp8((int)x, true);
    f32x2 d2 = __builtin_amdgcn_cvt_pk_f32_fp8((int)y, false);
    f32x2 d3 = __builtin_amdgcn_cvt_pk_f32_fp8((int)y, true);
    ag[0] += d0[0]; ag[1] += d0[1];
    ag[2] += d1[0]; ag[3] += d1[1];
    ag[4] += d2[0]; ag[5] += d2[1];
    ag[6] += d3[0]; ag[7] += d3[1];
}
// permuted fp8 offset for fragment (q,kk) within a row
__device__ __forceinline__ int fp8_off(int q, int kk){
    return (kk < 2) ? (q * 16 + kk * 8) : (64 + q * 16 + (kk - 2) * 8);
}
__device__ __forceinline__ void lds_fence(){
    asm volatile("s_waitcnt lgkmcnt(0)" ::: "memory");
    __builtin_amdgcn_sched_barrier(0);
}

// ---------------- weight pre-convert (merged) ----------------
__global__ __launch_bounds__(256) void k_splitall(const float* __restrict__ W_in, const float* __restrict__ sWl,
                                                  const float* __restrict__ sWr, const float* __restrict__ ipW,
                                                  u16* __restrict__ Win, u16* __restrict__ Wl,
                                                  u16* __restrict__ Wr, u16* __restrict__ Wv){
    const int WSZ = H * H;
    int i = blockIdx.x * 256 + threadIdx.x;
    if (i < WSZ)               Win[i]           = f2b(W_in[i]);
    else if (i < 4 * WSZ)      Wl[i - WSZ]      = f2b(sWl[i - WSZ]);
    else if (i < 7 * WSZ)      Wr[i - 4 * WSZ]  = f2b(sWr[i - 4 * WSZ]);
    else if (i < 8 * WSZ)      Wv[i - 7 * WSZ]  = f2b(ipW[2 * WSZ + (i - 7 * WSZ)]);
}

// ---------------- bucketed CSR build ----------------
__global__ __launch_bounds__(1024) void k_bcnt(const int* __restrict__ dst, int* __restrict__ bcnt,
                                               int E, int NBK){
    __shared__ int cnt[256];
    int tid = threadIdx.x;
    if (tid < 256) cnt[tid] = 0;
    __syncthreads();
    int e0 = blockIdx.x * CH;
    int n = min(CH, E - e0);
    for (int j = tid; j < n; j += 1024) atomicAdd(&cnt[dst[e0 + j] >> BKSH], 1);
    __syncthreads();
    if (tid < NBK && cnt[tid]) atomicAdd(&bcnt[tid], cnt[tid]);
}

__global__ __launch_bounds__(256) void k_bscan(const int* __restrict__ bcnt, int* __restrict__ boff,
                                               int* __restrict__ bcur, int* __restrict__ offs, int NBK, int N){
    __shared__ int pre[256];
    int tid = threadIdx.x;
    int v = (tid < NBK) ? bcnt[tid] : 0;
    pre[tid] = v;
    __syncthreads();
    for (int off = 1; off < 256; off <<= 1){
        int a = (tid >= off) ? pre[tid - off] : 0;
        __syncthreads();
        pre[tid] += a;
        __syncthreads();
    }
    int excl = pre[tid] - v;
    if (tid < NBK){ boff[tid] = excl; bcur[tid] = excl; }
    if (tid == 255){
        boff[NBK] = pre[255];
        offs[N] = pre[255];
    }
}

__global__ __launch_bounds__(1024) void k_bscatter(const int* __restrict__ src, const int* __restrict__ dst,
                                                   unsigned* __restrict__ ebuf, int* __restrict__ bcur,
                                                   int E, int NBK){
    __shared__ int cnt[256], pre[256], loc[256], lcur[256], base[256];
    __shared__ unsigned stage[CH];
    int tid = threadIdx.x;
    if (tid < 256){ cnt[tid] = 0; }
    __syncthreads();
    int e0 = blockIdx.x * CH;
    int n = min(CH, E - e0);
    for (int j = tid; j < n; j += 1024) atomicAdd(&cnt[dst[e0 + j] >> BKSH], 1);
    __syncthreads();
    if (tid < NBK) base[tid] = atomicAdd(&bcur[tid], cnt[tid]);
    if (tid < 256) pre[tid] = cnt[tid];
    __syncthreads();
    for (int off = 1; off < 256; off <<= 1){
        int v = (tid < 256 && tid >= off) ? pre[tid - off] : 0;
        __syncthreads();
        if (tid < 256) pre[tid] += v;
        __syncthreads();
    }
    if (tid < 256){ loc[tid] = pre[tid] - cnt[tid]; lcur[tid] = loc[tid]; }
    __syncthreads();
    for (int j = tid; j < n; j += 1024){
        int d = dst[e0 + j], s = src[e0 + j];
        int k = d >> BKSH;
        int p = atomicAdd(&lcur[k], 1);
        stage[p] = (unsigned)d | ((unsigned)s << 16);
    }
    __syncthreads();
    for (int j = tid; j < n; j += 1024){
        unsigned v = stage[j];
        int k = (v & 0xffffu) >> BKSH;
        ebuf[base[k] + (j - loc[k])] = v;
    }
}

__global__ __launch_bounds__(256) void k_bfill(const unsigned* __restrict__ ebuf, const int* __restrict__ boff,
                                               int* __restrict__ offs, int* __restrict__ csr,
                                               float* __restrict__ invdeg, int N){
    __shared__ int deg[256], pre[256], cur[256];
    int k = blockIdx.x, tid = threadIdx.x;
    int node0 = k << BKSH;
    int s0 = boff[k], s1 = boff[k + 1];
    deg[tid] = 0;
    __syncthreads();
    for (int j = s0 + tid; j < s1; j += 256) atomicAdd(&deg[ebuf[j] & 255u], 1);
    __syncthreads();
    pre[tid] = deg[tid];
    __syncthreads();
    for (int off = 1; off < 256; off <<= 1){
        int v = (tid >= off) ? pre[tid - off] : 0;
        __syncthreads();
        pre[tid] += v;
        __syncthreads();
    }
    int excl = pre[tid] - deg[tid];
    int node = node0 + tid;
    if (node < N){
        offs[node] = s0 + excl;
        invdeg[node] = 1.0f / (float)max(deg[tid], 1);
    }
    cur[tid] = s0 + excl;
    __syncthreads();
    for (int j = s0 + tid; j < s1; j += 256){
        unsigned v = ebuf[j];
        int p = atomicAdd(&cur[v & 255u], 1);
        csr[p] = (int)(v >> 16);
    }
}

__global__ void k_start(const int* __restrict__ batch, int* __restrict__ start, int N, int B){
    int n = blockIdx.x * blockDim.x + threadIdx.x;
    if (n >= N) return;
    int b = batch[n];
    int bp = (n == 0) ? -1 : batch[n - 1];
    for (int g = bp + 1; g <= b; g++) start[g] = n;
    if (n == N - 1){ for (int g = b + 1; g <= B; g++) start[g] = N; }
}

// ---------------- input projection GEMM (coalesced stage + stores) ----------------
__global__ __launch_bounds__(256) void k_gemm0(const float* __restrict__ A, u16* __restrict__ Xb,
                                               u8* __restrict__ X8,
                                               const u16* __restrict__ W1, const float* __restrict__ bias,
                                               int nrows){
    __shared__ float lt[4][16 * 132];       // per-wave f32 tile; staged bf16 aliases first half
    const int wave = threadIdx.x >> 6;
    const int l = threadIdx.x & 63;
    const int q = l >> 4;
    const int t = l & 15;
    const int row0 = blockIdx.x * 64 + wave * 16;

    // coalesced stage: 16 rows x 128 f32 -> bf16 LDS tile (stride 136 u16, 16B-aligned rows)
    u16* sw = (u16*)&lt[wave][0];
    #pragma unroll
    for (int i = 0; i < 8; i++){
        int p = (i * 64 + l) * 4;          // f32 linear index in tile
        int row = p >> 7, col = p & 127;
        int rowg = min(row0 + row, nrows - 1);
        float4 v = *(const float4*)(A + (size_t)rowg * H + col);
        u16* d = sw + row * 136 + col;
        d[0] = f2b(v.x); d[1] = f2b(v.y); d[2] = f2b(v.z); d[3] = f2b(v.w);
    }
    lds_fence();
    bf16x8 a1[4];
    #pragma unroll
    for (int kk = 0; kk < 4; kk++)
        a1[kk] = *(const bf16x8*)(sw + t * 136 + q * 8 + kk * 32);
    lds_fence();

    f32x4 acc[8];
    #pragma unroll
    for (int nt = 0; nt < 8; nt++){
        f32x4 c = {0.f, 0.f, 0.f, 0.f};
        const size_t wof = (size_t)(nt * 16 + t) * H + q * 8;
        #pragma unroll
        for (int kk = 0; kk < 4; kk++)
            c = __builtin_amdgcn_mfma_f32_16x16x32_bf16(a1[kk], *(const bf16x8*)(W1 + wof + kk * 32), c, 0, 0, 0);
        acc[nt] = c;
    }
    float bv[8];
    #pragma unroll
    for (int nt = 0; nt < 8; nt++) bv[nt] = bias[nt * 16 + t];
    #pragma unroll
    for (int r = 0; r < 4; r++)
        #pragma unroll
        for (int nt = 0; nt < 8; nt++)
            lt[wave][(q * 4 + r) * 132 + nt * 16 + t] = fmaxf(acc[nt][r] + bv[nt], 0.f);
    lds_fence();
    // coalesced phase 2: linear lane mapping, contiguous stores
    #pragma unroll
    for (int i = 0; i < 4; i++){
        int p = (i * 64 + l) * 8;          // u16 linear index in tile
        int row = p >> 7, col = p & 127;
        int rg = row0 + row;
        if (rg < nrows){
            const float* lp = &lt[wave][row * 132 + col];
            float4 v0 = *(const float4*)lp;
            float4 v1 = *(const float4*)(lp + 4);
            float nv[8] = {v0.x, v0.y, v0.z, v0.w, v1.x, v1.y, v1.z, v1.w};
            bf16x8 o;
            #pragma unroll
            for (int j = 0; j < 8; j++) o[j] = (short)f2b(nv[j]);
            *(bf16x8*)(Xb + (size_t)rg * H + col) = o;
            *(uint2*)(X8 + (size_t)rg * H + fp8_off((col & 31) >> 3, col >> 5)) = pk_fp8(nv);
        }
    }
}

// ---------------- fused layer: staged a2 + 2-wave split fp8 gather + SAGE GEMM + LN + relu + residual ----------------
// Block = 128 thr (2 waves). Coalesced Xin stage into sx feeds a2 frags + residual.
// Wave0: half-list gather + GEMM + epilogue. Wave1: other half -> partial -> retire.
template<bool FSC>
__global__ __launch_bounds__(128) void k_layer(
    const u16* __restrict__ Xin, const u8* __restrict__ Xin8,
    u16* __restrict__ Xout, u8* __restrict__ Xout8,
    const int* __restrict__ offs, const int* __restrict__ csr, const float* __restrict__ invdeg,
    const u16* __restrict__ W1, const u16* __restrict__ W2,
    const float* __restrict__ bias, const float* __restrict__ lng, const float* __restrict__ lnb,
    u16* __restrict__ Vb, const u16* __restrict__ Wv, const float* __restrict__ vbias,
    const float* __restrict__ qk, const float* __restrict__ qkb, float* __restrict__ scores,
    int nrows)
{
    __shared__ float ltw[16 * 132];
    __shared__ u16 sx[16 * 136];
    const int wave = threadIdx.x >> 6;
    const int l = threadIdx.x & 63;
    const int q = l >> 4;
    const int t = l & 15;
    const int row0g = blockIdx.x * 16;
    const int myrow = row0g + t;
    const bool valid = myrow < nrows;

    // cooperative coalesced stage of the block's 16 Xin rows (bf16)
    #pragma unroll
    for (int i = 0; i < 2; i++){
        int p = (i * 128 + threadIdx.x) * 8;   // u16 linear
        int row = p >> 7, col = p & 127;
        int rowg = min(row0g + row, nrows - 1);
        uint4 v = *(const uint4*)(Xin + (size_t)rowg * H + col);
        *(uint4*)(sx + row * 136 + col) = v;
    }
    __syncthreads();
    // a2 fragments from LDS (wave0 only)
    bf16x8 a2[4];
    if (wave == 0){
        #pragma unroll
        for (int kk = 0; kk < 4; kk++)
            a2[kk] = *(const bf16x8*)(sx + t * 136 + q * 8 + kk * 32);
    }
    // fp8 permuted gather over this wave's half of the list
    float ag[4][8];
    #pragma unroll
    for (int kk = 0; kk < 4; kk++)
        #pragma unroll
        for (int j = 0; j < 8; j++) ag[kk][j] = 0.f;
    int o0 = valid ? offs[myrow] : 0;
    int o1 = valid ? offs[myrow + 1] : 0;
    int mid = o0 + ((o1 - o0 + 1) >> 1);
    int i  = wave ? mid : o0;
    int ie = wave ? o1 : mid;
    int p0 = 0, p1 = 0, p2 = 0, p3 = 0;
    if (i + 3 < ie){ p0 = csr[i]; p1 = csr[i + 1]; p2 = csr[i + 2]; p3 = csr[i + 3]; }
    while (i + 3 < ie){
        int t0 = p0, t1 = p1, t2 = p2, t3 = p3;
        int nx = i + 4;
        if (nx + 3 < ie){ p0 = csr[nx]; p1 = csr[nx + 1]; p2 = csr[nx + 2]; p3 = csr[nx + 3]; }
        const u8* g0 = Xin8 + (size_t)t0 * H + q * 16;
        const u8* g1 = Xin8 + (size_t)t1 * H + q * 16;
        const u8* g2 = Xin8 + (size_t)t2 * H + q * 16;
        const u8* g3 = Xin8 + (size_t)t3 * H + q * 16;
        uint4 a0 = *(const uint4*)(g0);
        uint4 b0 = *(const uint4*)(g0 + 64);
        uint4 a1v = *(const uint4*)(g1);
        uint4 b1 = *(const uint4*)(g1 + 64);
        uint4 a2v = *(const uint4*)(g2);
        uint4 b2 = *(const uint4*)(g2 + 64);
        uint4 a3 = *(const uint4*)(g3);
        uint4 b3 = *(const uint4*)(g3 + 64);
        acc_fp8w(ag[0], a0.x, a0.y);  acc_fp8w(ag[1], a0.z, a0.w);
        acc_fp8w(ag[2], b0.x, b0.y);  acc_fp8w(ag[3], b0.z, b0.w);
        acc_fp8w(ag[0], a1v.x, a1v.y); acc_fp8w(ag[1], a1v.z, a1v.w);
        acc_fp8w(ag[2], b1.x, b1.y);  acc_fp8w(ag[3], b1.z, b1.w);
        acc_fp8w(ag[0], a2v.x, a2v.y); acc_fp8w(ag[1], a2v.z, a2v.w);
        acc_fp8w(ag[2], b2.x, b2.y);  acc_fp8w(ag[3], b2.z, b2.w);
        acc_fp8w(ag[0], a3.x, a3.y);  acc_fp8w(ag[1], a3.z, a3.w);
        acc_fp8w(ag[2], b3.x, b3.y);  acc_fp8w(ag[3], b3.z, b3.w);
        i = nx;
    }
    for (; i < ie; i++){
        int s = csr[i];
        const u8* gp = Xin8 + (size_t)s * H + q * 16;
        uint4 wa = *(const uint4*)(gp);
        uint4 wb = *(const uint4*)(gp + 64);
        acc_fp8w(ag[0], wa.x, wa.y);  acc_fp8w(ag[1], wa.z, wa.w);
        acc_fp8w(ag[2], wb.x, wb.y);  acc_fp8w(ag[3], wb.z, wb.w);
    }
    // wave1 deposits partial into ltw (A-layout: row t, col q*8+kk*32+j)
    if (wave == 1){
        float* pw = ltw + t * 132 + q * 8;
        #pragma unroll
        for (int kk = 0; kk < 4; kk++)
            #pragma unroll
            for (int j = 0; j < 8; j++) pw[kk * 32 + j] = ag[kk][j];
    }
    __syncthreads();
    if (wave == 1) return;
    // wave0: combine partial
    {
        const float* pr = ltw + t * 132 + q * 8;
        #pragma unroll
        for (int kk = 0; kk < 4; kk++)
            #pragma unroll
            for (int j = 0; j < 8; j++) ag[kk][j] += pr[kk * 32 + j];
    }
    lds_fence();
    float idg = valid ? invdeg[myrow] : 0.f;
    bf16x8 a1[4];
    #pragma unroll
    for (int kk = 0; kk < 4; kk++){
        bf16x8 v;
        #pragma unroll
        for (int j = 0; j < 8; j++) v[j] = (short)f2b(ag[kk][j] * idg);
        a1[kk] = v;
    }

    // GEMM: agg@W1^T + x@W2^T
    f32x4 acc[8];
    #pragma unroll
    for (int nt = 0; nt < 8; nt++){
        f32x4 c = {0.f, 0.f, 0.f, 0.f};
        const size_t wof = (size_t)(nt * 16 + t) * H + q * 8;
        #pragma unroll
        for (int kk = 0; kk < 4; kk++)
            c = __builtin_amdgcn_mfma_f32_16x16x32_bf16(a1[kk], *(const bf16x8*)(W1 + wof + kk * 32), c, 0, 0, 0);
        #pragma unroll
        for (int kk = 0; kk < 4; kk++)
            c = __builtin_amdgcn_mfma_f32_16x16x32_bf16(a2[kk], *(const bf16x8*)(W2 + wof + kk * 32), c, 0, 0, 0);
        acc[nt] = c;
    }
    float bv[8], gv[8], lbv[8];
    #pragma unroll
    for (int nt = 0; nt < 8; nt++){
        int col = nt * 16 + t;
        bv[nt] = bias[col]; gv[nt] = lng[col]; lbv[nt] = lnb[col];
    }
    // phase 1: LN + relu into ltw
    #pragma unroll
    for (int r = 0; r < 4; r++){
        float hv[8], s = 0.f, s2 = 0.f;
        #pragma unroll
        for (int nt = 0; nt < 8; nt++){ float v = acc[nt][r] + bv[nt]; hv[nt] = v; s += v; s2 += v * v; }
        #pragma unroll
        for (int m = 1; m < 16; m <<= 1){ s += __shfl_xor(s, m, 64); s2 += __shfl_xor(s2, m, 64); }
        float mean = s * (1.f / H);
        float var  = s2 * (1.f / H) - mean * mean;
        float rstd = rsqrtf(var + 1e-5f);
        #pragma unroll
        for (int nt = 0; nt < 8; nt++){
            float v = (hv[nt] - mean) * rstd * gv[nt] + lbv[nt];
            ltw[(q * 4 + r) * 132 + nt * 16 + t] = fmaxf(v, 0.f);
        }
    }
    lds_fence();
    if (!FSC){
        // coalesced phase 2: linear lane mapping; residual from sx; contiguous stores
        #pragma unroll
        for (int i2 = 0; i2 < 4; i2++){
            int p = (i2 * 64 + l) * 8;
            int row = p >> 7, col = p & 127;
            int rg = row0g + row;
            if (rg < nrows){
                const float* lp = ltw + row * 132 + col;
                float4 v0 = *(const float4*)lp;
                float4 v1 = *(const float4*)(lp + 4);
                const u16* xp = sx + row * 136 + col;
                float nv[8];
                nv[0] = v0.x + b2f(xp[0]); nv[1] = v0.y + b2f(xp[1]);
                nv[2] = v0.z + b2f(xp[2]); nv[3] = v0.w + b2f(xp[3]);
                nv[4] = v1.x + b2f(xp[4]); nv[5] = v1.y + b2f(xp[5]);
                nv[6] = v1.z + b2f(xp[6]); nv[7] = v1.w + b2f(xp[7]);
                bf16x8 o;
                #pragma unroll
                for (int j = 0; j < 8; j++) o[j] = (short)f2b(nv[j]);
                *(bf16x8*)(Xout + (size_t)rg * H + col) = o;
                *(uint2*)(Xout8 + (size_t)rg * H + fp8_off((col & 31) >> 3, col >> 5)) = pk_fp8(nv);
            }
        }
    } else {
        // FSC phase 2: lane-layout (scores + fused V need fragment layout)
        bf16x8 xv[4];
        float sc[4] = {0.f, 0.f, 0.f, 0.f};
        #pragma unroll
        for (int kk = 0; kk < 4; kk++){
            const float* lp = ltw + t * 132 + q * 8 + kk * 32;
            float4 v0 = *(const float4*)lp;
            float4 v1 = *(const float4*)(lp + 4);
            float nv[8] = {v0.x, v0.y, v0.z, v0.w, v1.x, v1.y, v1.z, v1.w};
            #pragma unroll
            for (int j = 0; j < 8; j++) nv[j] += b2f((u16)a2[kk][j]);
            bf16x8 o;
            #pragma unroll
            for (int j = 0; j < 8; j++) o[j] = (short)f2b(nv[j]);
            xv[kk] = o;
            #pragma unroll
            for (int h = 0; h < 4; h++){
                const float* qp = qk + h * H + q * 8 + kk * 32;
                float4 q0 = *(const float4*)qp;
                float4 q1 = *(const float4*)(qp + 4);
                sc[h] += nv[0] * q0.x + nv[1] * q0.y + nv[2] * q0.z + nv[3] * q0.w
                       + nv[4] * q1.x + nv[5] * q1.y + nv[6] * q1.z + nv[7] * q1.w;
            }
        }
        #pragma unroll
        for (int h = 0; h < 4; h++){
            sc[h] += __shfl_xor(sc[h], 16, 64);
            sc[h] += __shfl_xor(sc[h], 32, 64);
        }
        if (q == 0 && valid){
            #pragma unroll
            for (int h = 0; h < 4; h++) scores[myrow * 4 + h] = sc[h] + qkb[h];
        }
        // fused V projection
        f32x4 vacc[8];
        #pragma unroll
        for (int nt = 0; nt < 8; nt++){
            f32x4 c = {0.f, 0.f, 0.f, 0.f};
            const size_t wof = (size_t)(nt * 16 + t) * H + q * 8;
            #pragma unroll
            for (int kk = 0; kk < 4; kk++)
                c = __builtin_amdgcn_mfma_f32_16x16x32_bf16(xv[kk], *(const bf16x8*)(Wv + wof + kk * 32), c, 0, 0, 0);
            vacc[nt] = c;
        }
        float vb2[8];
        #pragma unroll
        for (int nt = 0; nt < 8; nt++) vb2[nt] = vbias[nt * 16 + t];
        #pragma unroll
        for (int r = 0; r < 4; r++)
            #pragma unroll
            for (int nt = 0; nt < 8; nt++)
                ltw[(q * 4 + r) * 132 + nt * 16 + t] = vacc[nt][r] + vb2[nt];
        lds_fence();
        // coalesced Vb store
        #pragma unroll
        for (int i2 = 0; i2 < 4; i2++){
            int p = (i2 * 64 + l) * 8;
            int row = p >> 7, col = p & 127;
            int rg = row0g + row;
            if (rg < nrows){
                const float* lp = ltw + row * 132 + col;
                float4 v0 = *(const float4*)lp;
                float4 v1 = *(const float4*)(lp + 4);
                bf16x8 o;
                o[0] = (short)f2b(v0.x); o[1] = (short)f2b(v0.y);
                o[2] = (short)f2b(v0.z); o[3] = (short)f2b(v0.w);
                o[4] = (short)f2b(v1.x); o[5] = (short)f2b(v1.y);
                o[6] = (short)f2b(v1.z); o[7] = (short)f2b(v1.w);
                *(bf16x8*)(Vb + (size_t)rg * H + col) = o;
            }
        }
    }
}

// ---------------- attention fold ----------------
__global__ __launch_bounds__(128) void k_qk(const float* __restrict__ ipW, const float* __restrict__ ipb,
                                            const float* __restrict__ query,
                                            float* __restrict__ qk, float* __restrict__ qkb){
    __shared__ float qs[H];
    int t = threadIdx.x;
    float a = ipb[t];
    for (int c = 0; c < H; c++) a += ipW[t * H + c] * query[c];
    qs[t] = a;
    __syncthreads();
    const float r32 = 0.17677669529663687f;
    #pragma unroll
    for (int h = 0; h < 4; h++){
        float v = 0.f;
        for (int d = 0; d < 32; d++) v += ipW[(H + h * 32 + d) * H + t] * qs[h * 32 + d];
        qk[h * H + t] = v * r32;
    }
    if (t < 4){
        float z = 0.f;
        for (int d = 0; d < 32; d++) z += ipb[H + t * 32 + d] * qs[t * 32 + d];
        qkb[t] = z * r32;
    }
}

// ---------------- parallel softmax pool ----------------
__global__ __launch_bounds__(256) void k_smax(const float* __restrict__ scores, const int* __restrict__ start,
                                              float* __restrict__ smax, int B){
    int idx = blockIdx.x * 4 + (threadIdx.x >> 6);
    if (idx >= B * 4) return;
    int b = idx >> 2, h = idx & 3, l = threadIdx.x & 63;
    int s0 = start[b], s1 = start[b + 1];
    float m = -1e30f;
    for (int n = s0 + l; n < s1; n += 64) m = fmaxf(m, scores[n * 4 + h]);
    #pragma unroll
    for (int s = 1; s < 64; s <<= 1) m = fmaxf(m, __shfl_xor(m, s, 64));
    if (l == 0) smax[idx] = m;
}

__global__ __launch_bounds__(64) void k_poolsum(const float* __restrict__ scores, const u16* __restrict__ Vb,
                                                const int* __restrict__ start, const float* __restrict__ smax,
                                                float* __restrict__ praw, float* __restrict__ den){
    int b = blockIdx.x / PPG, p = blockIdx.x % PPG;
    int c2 = threadIdx.x;              // 0..63: cols 2*c2, 2*c2+1
    int h = c2 >> 4;
    int s0 = start[b], s1 = start[b + 1];
    float sm = smax[b * 4 + h];
    float a0 = 0.f, a1 = 0.f, se = 0.f;
    for (int n = s0 + p; n < s1; n += PPG){
        float e = expf(scores[n * 4 + h] - sm);
        unsigned wv = *(const unsigned*)(Vb + (size_t)n * H + 2 * c2);
        a0 += e * b2f((u16)(wv & 0xffffu));
        a1 += e * b2f((u16)(wv >> 16));
        se += e;
    }
    atomicAdd(&praw[b * H + 2 * c2], a0);
    atomicAdd(&praw[b * H + 2 * c2 + 1], a1);
    if ((c2 & 15) == 0) atomicAdd(&den[b * 4 + h], se);
}

// ---------------- tail ----------------
__global__ __launch_bounds__(128) void k_tail(
    const float* __restrict__ praw, const float* __restrict__ den,
    const float* __restrict__ outW, const float* __restrict__ outb,
    const float* __restrict__ symfeat, const float* __restrict__ symW, const float* __restrict__ symb,
    const float* __restrict__ sfW, const float* __restrict__ sfb, const float* __restrict__ sfg, const float* __restrict__ sfbeta,
    const float* __restrict__ fusW, const float* __restrict__ fusb, const float* __restrict__ fusg, const float* __restrict__ fusbeta,
    const float* __restrict__ hW1, const float* __restrict__ hb1, const float* __restrict__ hW2, const float* __restrict__ hb2,
    float* __restrict__ dout, int B){
    int b = blockIdx.x, t = threadIdx.x;
    __shared__ float P[H], G[H], EMB[H], S[H], F[H], HHs[192], red[H], mm[2];
    float dh = den[b * 4 + (t >> 5)];
    P[t] = (dh > 0.f) ? praw[b * H + t] / dh : 0.f;
    __syncthreads();
    float a = outb[t];
    for (int c = 0; c < H; c++) a += P[c] * outW[t * H + c];
    G[t] = a;
    {
        int f = t >> 5;
        float e = symb[t];
        for (int i = 0; i < 16; i++) e += symfeat[b * 64 + f * 16 + i] * symW[t * 16 + i];
        EMB[t] = fmaxf(e, 0.f);
    }
    __syncthreads();
    float a2 = sfb[t];
    for (int c = 0; c < H; c++) a2 += EMB[c] * sfW[t * H + c];
    a2 = fmaxf(a2, 0.f);
    red[t] = a2; __syncthreads();
    for (int s = 64; s > 0; s >>= 1){ if (t < s) red[t] += red[t + s]; __syncthreads(); }
    if (t == 0) mm[0] = red[0];
    __syncthreads();
    red[t] = a2 * a2; __syncthreads();
    for (int s = 64; s > 0; s >>= 1){ if (t < s) red[t] += red[t + s]; __syncthreads(); }
    if (t == 0) mm[1] = red[0];
    __syncthreads();
    {
        float mean = mm[0] * (1.f / H), var = mm[1] * (1.f / H) - mean * mean;
        float rstd = rsqrtf(var + 1e-5f);
        S[t] = (a2 - mean) * rstd * sfg[t] + sfbeta[t];
    }
    __syncthreads();
    float fu = fusb[t];
    for (int c = 0; c < H; c++) fu += G[c] * fusW[t * 256 + c];
    for (int c = 0; c < H; c++) fu += S[c] * fusW[t * 256 + 128 + c];
    fu = fmaxf(fu, 0.f);
    red[t] = fu; __syncthreads();
    for (int s = 64; s > 0; s >>= 1){ if (t < s) red[t] += red[t + s]; __syncthreads(); }
    if (t == 0) mm[0] = red[0];
    __syncthreads();
    red[t] = fu * fu; __syncthreads();
    for (int s = 64; s > 0; s >>= 1){ if (t < s) red[t] += red[t + s]; __syncthreads(); }
    if (t == 0) mm[1] = red[0];
    __syncthreads();
    {
        float mean = mm[0] * (1.f / H), var = mm[1] * (1.f / H) - mean * mean;
        float rstd = rsqrtf(var + 1e-5f);
        F[t] = (fu - mean) * rstd * fusg[t] + fusbeta[t];
    }
    __syncthreads();
    for (int idx = t; idx < 192; idx += 128){
        float hv = hb1[idx];
        for (int c = 0; c < H; c++) hv += F[c] * hW1[idx * H + c];
        HHs[idx] = fmaxf(hv, 0.f);
    }
    __syncthreads();
    if (t < 3){
        float z = hb2[t];
        for (int o = 0; o < 64; o++) z += HHs[t * 64 + o] * hW2[t * 64 + o];
        dout[t * B + b] = 1.f / (1.f + expf(-z));
    }
}

extern "C" void kernel_launch(void* const* d_in, const int* in_sizes, int n_in,
                              void* d_out, int out_size, void* d_ws, size_t ws_size,
                              hipStream_t stream){
    const float* NF      = (const float*)d_in[0];
    const float* SYMF    = (const float*)d_in[1];
    const int*   EIDX    = (const int*)d_in[2];
    const int*   BATCH   = (const int*)d_in[3];
    const float* W_in    = (const float*)d_in[4];
    const float* b_in    = (const float*)d_in[5];
    const float* sWl     = (const float*)d_in[6];
    const float* sbl     = (const float*)d_in[7];
    const float* sWr     = (const float*)d_in[8];
    const float* lng     = (const float*)d_in[9];
    const float* lnb     = (const float*)d_in[10];
    const float* query   = (const float*)d_in[11];
    const float* ipW     = (const float*)d_in[12];
    const float* ipb     = (const float*)d_in[13];
    const float* outW    = (const float*)d_in[14];
    const float* outb    = (const float*)d_in[15];
    const float* symW    = (const float*)d_in[16];
    const float* symb    = (const float*)d_in[17];
    const float* sfW     = (const float*)d_in[18];
    const float* sfb     = (const float*)d_in[19];
    const float* sfg     = (const float*)d_in[20];
    const float* sfbeta  = (const float*)d_in[21];
    const float* fusW    = (const float*)d_in[22];
    const float* fusb    = (const float*)d_in[23];
    const float* fusg    = (const float*)d_in[24];
    const float* fusbeta = (const float*)d_in[25];
    const float* hW1     = (const float*)d_in[26];
    const float* hb1     = (const float*)d_in[27];
    const float* hW2     = (const float*)d_in[28];
    const float* hb2     = (const float*)d_in[29];

    const int N = in_sizes[0] / H;
    const int E = in_sizes[2] / 2;
    const int B = in_sizes[1] / 64;
    const int* esrc = EIDX;
    const int* edst = EIDX + E;
    const int NBK = (N + 255) >> BKSH;

    char* w = (char*)d_ws;
    auto alloc = [&](size_t bytes) -> char* {
        char* p = w; w += (bytes + 255) & ~(size_t)255; return p;
    };
    u16*   X0      = (u16*)alloc((size_t)N * H * 2);
    u16*   X1      = (u16*)alloc((size_t)N * H * 2);
    u8*    X0q     = (u8*)alloc((size_t)N * H);
    u8*    X1q     = (u8*)alloc((size_t)N * H);
    u16*   Vb      = (u16*)alloc((size_t)N * H * 2);
    float* scores  = (float*)alloc((size_t)N * 4 * 4);
    unsigned* ebuf = (unsigned*)alloc((size_t)E * 4);
    char* zbase    = w;
    int* bcnt      = (int*)alloc((size_t)NBK * 4);
    float* praw    = (float*)alloc((size_t)B * H * 4);
    float* den     = (float*)alloc((size_t)B * 4 * 4);
    size_t zbytes  = (size_t)(w - zbase);
    int* boff      = (int*)alloc((size_t)(NBK + 1) * 4);
    int* bcur      = (int*)alloc((size_t)NBK * 4);
    int* offs      = (int*)alloc((size_t)(N + 1) * 4);
    float* invdeg  = (float*)alloc((size_t)N * 4);
    int* csr       = (int*)alloc((size_t)E * 4);
    int* start     = (int*)alloc((size_t)(B + 1) * 4);
    float* smax    = (float*)alloc((size_t)B * 4 * 4);
    float* qk      = (float*)alloc((size_t)4 * H * 4);
    float* qkb     = (float*)alloc(4 * 4);
    const int WSZ  = H * H;
    u16* Win = (u16*)alloc(WSZ * 2);
    u16* Wl  = (u16*)alloc(3 * WSZ * 2);
    u16* Wr  = (u16*)alloc(3 * WSZ * 2);
    u16* Wv  = (u16*)alloc(WSZ * 2);

    hipMemsetAsync(zbase, 0, zbytes, stream);

    const int cb = (E + CH - 1) / CH;
    k_bcnt<<<cb, 1024, 0, stream>>>(edst, bcnt, E, NBK);
    k_bscan<<<1, 256, 0, stream>>>(bcnt, boff, bcur, offs, NBK, N);
    k_bscatter<<<cb, 1024, 0, stream>>>(esrc, edst, ebuf, bcur, E, NBK);
    k_bfill<<<NBK, 256, 0, stream>>>(ebuf, boff, offs, csr, invdeg, N);
    k_start<<<(N + 255) / 256, 256, 0, stream>>>(BATCH, start, N, B);
    k_qk<<<1, 128, 0, stream>>>(ipW, ipb, query, qk, qkb);
    k_splitall<<<(8 * WSZ + 255) / 256, 256, 0, stream>>>(W_in, sWl, sWr, ipW, Win, Wl, Wr, Wv);

    const int gb = (N + 63) / 64;
    const int lb = (N + 15) / 16;
    k_gemm0<<<gb, 256, 0, stream>>>(NF, X0, X0q, Win, b_in, N);
    // layer 0: X0 -> X1 ; layer 1: X1 -> X0 ; layer 2 (FSC): X0 -> (scores, Vb)
    k_layer<false><<<lb, 128, 0, stream>>>(X0, X0q, X1, X1q, offs, csr, invdeg,
                                           Wl + 0 * WSZ, Wr + 0 * WSZ,
                                           sbl + 0 * H, lng + 0 * H, lnb + 0 * H,
                                           nullptr, nullptr, nullptr,
                                           nullptr, nullptr, nullptr, N);
    k_layer<false><<<lb, 128, 0, stream>>>(X1, X1q, X0, X0q, offs, csr, invdeg,
                                           Wl + 1 * WSZ, Wr + 1 * WSZ,
                                           sbl + 1 * H, lng + 1 * H, lnb + 1 * H,
                                           nullptr, nullptr, nullptr,
                                           nullptr, nullptr, nullptr, N);
    k_layer<true><<<lb, 128, 0, stream>>>(X0, X0q, nullptr, nullptr, offs, csr, invdeg,
                                          Wl + 2 * WSZ, Wr + 2 * WSZ,
                                          sbl + 2 * H, lng + 2 * H, lnb + 2 * H,
                                          Vb, Wv, ipb + 2 * H,
                                          qk, qkb, scores, N);
    k_smax<<<B, 256, 0, stream>>>(scores, start, smax, B);
    k_poolsum<<<B * PPG, 64, 0, stream>>>(scores, Vb, start, smax, praw, den);
    k_tail<<<B, 128, 0, stream>>>(praw, den, outW, outb, SYMF, symW, symb,
                                  sfW, sfb, sfg, sfbeta, fusW, fusb, fusg, fusbeta,
                                  hW1, hb1, hW2, hb2, (float*)d_out, B);
}